// Round 8
// baseline (91.911 us; speedup 1.0000x reference)
//
#include <hip/hip_runtime.h>
#include <math.h>

typedef float f32x2 __attribute__((ext_vector_type(2)));

#define NCH 96      // B*C = 32*3
#define HH 512
#define WW 512
#define OH 502      // valid output rows/cols
#define STRIP 64    // output rows per block (last strip = 54)
#define NSTRIP 8
#define NT 256      // threads; thread t owns output cols 2t, 2t+1 (t<=250)

struct Win { float w[11]; };
struct RawRow { f32x2 q0, q1, q2, q3, q4, q5; };
struct HRow { f32x2 am, as2, bm, bs; };   // (x,y)-blur and (s,p)-blur for cols A=2t, B=2t+1

__device__ __forceinline__ f32x2 pkfma(f32x2 a, f32x2 b, f32x2 c) {
    return __builtin_elementwise_fma(a, b, c);
}
__device__ __forceinline__ f32x2 pkfmas(f32x2 a, float s, f32x2 c) {
    f32x2 sv = {s, s};
    return __builtin_elementwise_fma(a, sv, c);
}
__device__ __forceinline__ f32x2 pkmuls(f32x2 a, float s) {
    f32x2 sv = {s, s};
    return a * sv;
}

__device__ __forceinline__ float ssim_px(float m1, float m2, float ms, float mp) {
    const float C1v = 1e-4f;   // (0.01)^2
    const float C2v = 9e-4f;   // (0.03)^2
    float mu12  = m1 * m2;
    float musum = fmaf(m1, m1, m2 * m2);
    float num = fmaf(2.f, mp - mu12, C2v) * fmaf(2.f, mu12, C1v);
    float den = ((ms - musum) + C2v) * (musum + C1v);   // > 0 always
    return num * __builtin_amdgcn_rcpf(den);
}

__device__ __forceinline__ RawRow load_row(const float* __restrict__ p) {
    RawRow r;
    r.q0 = *(const f32x2*)(p + 0);  r.q1 = *(const f32x2*)(p + 2);
    r.q2 = *(const f32x2*)(p + 4);  r.q3 = *(const f32x2*)(p + 6);
    r.q4 = *(const f32x2*)(p + 8);  r.q5 = *(const f32x2*)(p + 10);
    return r;
}

// scalar 11-tap chain
#define HCHAIN(q0,q1,q2,q3,q4,q5,q6,q7,q8,q9,q10) \
  fmaf(w10,(q10),fmaf(w9,(q9),fmaf(w8,(q8),fmaf(w7,(q7),fmaf(w6,(q6),fmaf(w5,(q5), \
  fmaf(w4,(q4),fmaf(w3,(q3),fmaf(w2,(q2),fmaf(w1,(q1),w0*(q0)))))))))))

// horizontal blur of one raw row: normalize, form s=x^2+y^2, p=x*y, 11-tap for cols A,B
__device__ __forceinline__ HRow hblur_from(const RawRow& rx, const RawRow& ry, const Win& win) {
    const float w0 = win.w[0], w1 = win.w[1], w2 = win.w[2], w3 = win.w[3];
    const float w4 = win.w[4], w5 = win.w[5], w6 = win.w[6], w7 = win.w[7];
    const float w8 = win.w[8], w9 = win.w[9], w10 = win.w[10];
    const f32x2 h2 = {0.5f, 0.5f};
    f32x2 nx0 = pkfma(rx.q0, h2, h2), nx1 = pkfma(rx.q1, h2, h2), nx2 = pkfma(rx.q2, h2, h2);
    f32x2 nx3 = pkfma(rx.q3, h2, h2), nx4 = pkfma(rx.q4, h2, h2), nx5 = pkfma(rx.q5, h2, h2);
    f32x2 ny0 = pkfma(ry.q0, h2, h2), ny1 = pkfma(ry.q1, h2, h2), ny2 = pkfma(ry.q2, h2, h2);
    f32x2 ny3 = pkfma(ry.q3, h2, h2), ny4 = pkfma(ry.q4, h2, h2), ny5 = pkfma(ry.q5, h2, h2);
    f32x2 ns0 = pkfma(ny0, ny0, nx0 * nx0), ns1 = pkfma(ny1, ny1, nx1 * nx1);
    f32x2 ns2 = pkfma(ny2, ny2, nx2 * nx2), ns3 = pkfma(ny3, ny3, nx3 * nx3);
    f32x2 ns4 = pkfma(ny4, ny4, nx4 * nx4), ns5 = pkfma(ny5, ny5, nx5 * nx5);
    f32x2 np0 = nx0 * ny0, np1 = nx1 * ny1, np2 = nx2 * ny2;
    f32x2 np3 = nx3 * ny3, np4 = nx4 * ny4, np5 = nx5 * ny5;
    HRow h;
    h.am = (f32x2){
        HCHAIN(nx0.x,nx0.y,nx1.x,nx1.y,nx2.x,nx2.y,nx3.x,nx3.y,nx4.x,nx4.y,nx5.x),
        HCHAIN(ny0.x,ny0.y,ny1.x,ny1.y,ny2.x,ny2.y,ny3.x,ny3.y,ny4.x,ny4.y,ny5.x) };
    h.bm = (f32x2){
        HCHAIN(nx0.y,nx1.x,nx1.y,nx2.x,nx2.y,nx3.x,nx3.y,nx4.x,nx4.y,nx5.x,nx5.y),
        HCHAIN(ny0.y,ny1.x,ny1.y,ny2.x,ny2.y,ny3.x,ny3.y,ny4.x,ny4.y,ny5.x,ny5.y) };
    h.as2 = (f32x2){
        HCHAIN(ns0.x,ns0.y,ns1.x,ns1.y,ns2.x,ns2.y,ns3.x,ns3.y,ns4.x,ns4.y,ns5.x),
        HCHAIN(np0.x,np0.y,np1.x,np1.y,np2.x,np2.y,np3.x,np3.y,np4.x,np4.y,np5.x) };
    h.bs = (f32x2){
        HCHAIN(ns0.y,ns1.x,ns1.y,ns2.x,ns2.y,ns3.x,ns3.y,ns4.x,ns4.y,ns5.x,ns5.y),
        HCHAIN(np0.y,np1.x,np1.y,np2.x,np2.y,np3.x,np3.y,np4.x,np4.y,np5.x,np5.y) };
    return h;
}

// One output row RIDX (strip-relative). Ring slots S0..S9 hold hblur rows RIDX..RIDX+9.
// Fresh hblur of row RIDX+10 finishes the vblur and replaces slot S0.
#define PHASE(RIDX, S0,S1,S2,S3,S4,S5,S6,S7,S8,S9) do {                          \
    RawRow rx_ = load_row(xbase + (size_t)((RIDX) + 10) * WW);                   \
    RawRow ry_ = load_row(ybase + (size_t)((RIDX) + 10) * WW);                   \
    f32x2 vAm = pkmuls(Am[S0], w0), vAs = pkmuls(As[S0], w0);                    \
    f32x2 vBm = pkmuls(Bm[S0], w0), vBs = pkmuls(Bs[S0], w0);                    \
    vAm = pkfmas(Am[S1], w1, vAm); vAs = pkfmas(As[S1], w1, vAs);                \
    vBm = pkfmas(Bm[S1], w1, vBm); vBs = pkfmas(Bs[S1], w1, vBs);                \
    vAm = pkfmas(Am[S2], w2, vAm); vAs = pkfmas(As[S2], w2, vAs);                \
    vBm = pkfmas(Bm[S2], w2, vBm); vBs = pkfmas(Bs[S2], w2, vBs);                \
    vAm = pkfmas(Am[S3], w3, vAm); vAs = pkfmas(As[S3], w3, vAs);                \
    vBm = pkfmas(Bm[S3], w3, vBm); vBs = pkfmas(Bs[S3], w3, vBs);                \
    vAm = pkfmas(Am[S4], w4, vAm); vAs = pkfmas(As[S4], w4, vAs);                \
    vBm = pkfmas(Bm[S4], w4, vBm); vBs = pkfmas(Bs[S4], w4, vBs);                \
    vAm = pkfmas(Am[S5], w5, vAm); vAs = pkfmas(As[S5], w5, vAs);                \
    vBm = pkfmas(Bm[S5], w5, vBm); vBs = pkfmas(Bs[S5], w5, vBs);                \
    vAm = pkfmas(Am[S6], w6, vAm); vAs = pkfmas(As[S6], w6, vAs);                \
    vBm = pkfmas(Bm[S6], w6, vBm); vBs = pkfmas(Bs[S6], w6, vBs);                \
    vAm = pkfmas(Am[S7], w7, vAm); vAs = pkfmas(As[S7], w7, vAs);                \
    vBm = pkfmas(Bm[S7], w7, vBm); vBs = pkfmas(Bs[S7], w7, vBs);                \
    vAm = pkfmas(Am[S8], w8, vAm); vAs = pkfmas(As[S8], w8, vAs);                \
    vBm = pkfmas(Bm[S8], w8, vBm); vBs = pkfmas(Bs[S8], w8, vBs);                \
    vAm = pkfmas(Am[S9], w9, vAm); vAs = pkfmas(As[S9], w9, vAs);                \
    vBm = pkfmas(Bm[S9], w9, vBm); vBs = pkfmas(Bs[S9], w9, vBs);                \
    HRow f_ = hblur_from(rx_, ry_, win);                                         \
    vAm = pkfmas(f_.am, w10, vAm);  vAs = pkfmas(f_.as2, w10, vAs);              \
    vBm = pkfmas(f_.bm, w10, vBm);  vBs = pkfmas(f_.bs, w10, vBs);               \
    acc += ssim_px(vAm.x, vAm.y, vAs.x, vAs.y);                                  \
    acc += ssim_px(vBm.x, vBm.y, vBs.x, vBs.y);                                  \
    Am[S0] = f_.am; As[S0] = f_.as2; Bm[S0] = f_.bm; Bs[S0] = f_.bs;             \
} while (0)

__global__ __launch_bounds__(NT, 3)
void ssim_main(const float* __restrict__ X, const float* __restrict__ Y,
               float* __restrict__ partial, Win win) {
    __shared__ float red[4];

    const int b     = blockIdx.x;
    const int ch    = b >> 3;         // / NSTRIP
    const int strip = b & 7;
    const int r0    = strip * STRIP;
    const int rows  = min(STRIP, OH - r0);   // 64 or 54; always >= 10
    const int t     = threadIdx.x;

    float acc = 0.f;

    if (t < 251) {   // thread t owns output cols 2t, 2t+1; needs raw cols 2t..2t+11
        const float w0 = win.w[0], w1 = win.w[1], w2 = win.w[2], w3 = win.w[3];
        const float w4 = win.w[4], w5 = win.w[5], w6 = win.w[6], w7 = win.w[7];
        const float w8 = win.w[8], w9 = win.w[9], w10 = win.w[10];

        const size_t choff = (size_t)ch * (HH * WW);
        const float* xbase = X + choff + (size_t)r0 * WW + 2 * t;
        const float* ybase = Y + choff + (size_t)r0 * WW + 2 * t;

        // 10-row ring of hblur outputs (4 f32x2 per row), fully register-resident;
        // all indices static via 10-phase rotation.
        f32x2 Am[10], As[10], Bm[10], Bs[10];

        #pragma unroll
        for (int i = 0; i < 10; ++i) {
            RawRow rx = load_row(xbase + (size_t)i * WW);
            RawRow ry = load_row(ybase + (size_t)i * WW);
            HRow f = hblur_from(rx, ry, win);
            Am[i] = f.am; As[i] = f.as2; Bm[i] = f.bm; Bs[i] = f.bs;
        }

        int r = 0;
        for (;;) {
            PHASE(r + 0, 0,1,2,3,4,5,6,7,8,9);  if (r + 2  > rows) break;
            PHASE(r + 1, 1,2,3,4,5,6,7,8,9,0);  if (r + 3  > rows) break;
            PHASE(r + 2, 2,3,4,5,6,7,8,9,0,1);  if (r + 4  > rows) break;
            PHASE(r + 3, 3,4,5,6,7,8,9,0,1,2);  if (r + 5  > rows) break;
            PHASE(r + 4, 4,5,6,7,8,9,0,1,2,3);  if (r + 6  > rows) break;
            PHASE(r + 5, 5,6,7,8,9,0,1,2,3,4);  if (r + 7  > rows) break;
            PHASE(r + 6, 6,7,8,9,0,1,2,3,4,5);  if (r + 8  > rows) break;
            PHASE(r + 7, 7,8,9,0,1,2,3,4,5,6);  if (r + 9  > rows) break;
            PHASE(r + 8, 8,9,0,1,2,3,4,5,6,7);  if (r + 10 > rows) break;
            PHASE(r + 9, 9,0,1,2,3,4,5,6,7,8);
            r += 10;  if (r >= rows) break;
        }
    }

    // block reduction -> one partial per block (no atomics: deterministic)
    #pragma unroll
    for (int m = 1; m < 64; m <<= 1) acc += __shfl_xor(acc, m, 64);
    if ((t & 63) == 0) red[t >> 6] = acc;
    __syncthreads();
    if (t == 0) partial[b] = (red[0] + red[1]) + (red[2] + red[3]);
}

__global__ __launch_bounds__(128)
void ssim_final(const float* __restrict__ partial, float* __restrict__ out) {
    const int t = threadIdx.x;  // 128 threads
    float v = 0.f;
    if (t < NCH) {
        float s = 0.f;
        #pragma unroll
        for (int i = 0; i < NSTRIP; ++i) s += partial[t * NSTRIP + i];
        s *= (1.f / (502.f * 502.f));   // per-channel spatial mean
        v = fmaxf(s, 0.f);              // relu (nonnegative_ssim)
    }
    #pragma unroll
    for (int m = 1; m < 64; m <<= 1) v += __shfl_xor(v, m, 64);
    __shared__ float r2[2];
    if ((t & 63) == 0) r2[t >> 6] = v;
    __syncthreads();
    if (t == 0) out[0] = 1.f - (r2[0] + r2[1]) * (1.f / (float)NCH);
}

extern "C" void kernel_launch(void* const* d_in, const int* in_sizes, int n_in,
                              void* d_out, int out_size, void* d_ws, size_t ws_size,
                              hipStream_t stream) {
    const float* X = (const float*)d_in[0];
    const float* Y = (const float*)d_in[1];
    float* out = (float*)d_out;
    float* partial = (float*)d_ws;   // NCH*NSTRIP = 768 floats

    Win win;
    double g[11], sum = 0.0;
    for (int i = 0; i < 11; ++i) {
        double c = (double)(i - 5);
        g[i] = exp(-(c * c) / (2.0 * 1.5 * 1.5));
        sum += g[i];
    }
    for (int i = 0; i < 11; ++i) win.w[i] = (float)(g[i] / sum);

    ssim_main<<<NCH * NSTRIP, NT, 0, stream>>>(X, Y, partial, win);
    ssim_final<<<1, 128, 0, stream>>>(partial, out);
}